// Round 3
// baseline (175.689 us; speedup 1.0000x reference)
//
#include <hip/hip_runtime.h>
#include <float.h>

// Problem constants (B=8, N=8192, D=3)
#define NB 8
#define NPTS 8192
#define TOTAL (NB * NPTS)            // 65536 adv points
#define BLK 256
#define APT 16                       // adv points per thread
#define OSPLIT 32                    // ori-dimension split (blocks per column)
#define OCHUNK (NPTS / OSPLIT)       // 256 ori points per block (4 KB LDS)
#define ADV_PER_BLOCK (BLK * APT)    // 4096
#define ADV_CHUNKS (NPTS / ADV_PER_BLOCK)   // 2
#define NCOL (NB * ADV_CHUNKS)       // 16 columns, each served by OSPLIT blocks
#define GRID_MAIN (NCOL * OSPLIT)    // 512 blocks -> 2 blocks/CU, 8 waves/CU
#define PART_BYTES ((size_t)OSPLIT * TOTAL * sizeof(float))  // 8 MB

// Single fused kernel.
//  Phase 1 (all 512 blocks): block = (batch b, advChunk, split). Stage 256 ori
//    points (x,y,z,0.5*|o|^2) in LDS; each thread owns 16 adv points in regs;
//    inner loop = 6 fmaf + 1 min3 per (2 ori x 1 adv) with one-iteration LDS
//    prefetch. Writes partial mins (d = ra + 2*min u) to ws.
//  Phase 2 (last block per column): min over the 32 splits + weighted sum.
//  Phase 3 (last column): sum 16 column sums, plain-store out[0].
__global__ __launch_bounds__(BLK) void chamfer_fused(const float* __restrict__ adv,
                                                     const float* __restrict__ ori,
                                                     const float* __restrict__ w,
                                                     float* __restrict__ partial,
                                                     float* __restrict__ colsum,
                                                     unsigned int* __restrict__ colCnt,
                                                     unsigned int* __restrict__ cnt2,
                                                     float* __restrict__ out) {
    const int bx = blockIdx.x;
    const int b = bx >> 6;                     // 64 blocks per batch
    const int rem = bx & 63;
    const int advChunk = rem & (ADV_CHUNKS - 1);
    const int split = rem >> 1;
    const int col = b * ADV_CHUNKS + advChunk;
    const int t = threadIdx.x;

    __shared__ float4 opts[OCHUNK];            // 4 KB
    __shared__ float red[BLK];                 // 1 KB (phase 2)
    __shared__ unsigned int ticket_s;

    // ---- stage ori chunk: one point per thread ----
    const float* orib = ori + ((size_t)b * NPTS + (size_t)split * OCHUNK) * 3;
    {
        float x = orib[3 * t + 0], y = orib[3 * t + 1], z = orib[3 * t + 2];
        opts[t] = make_float4(x, y, z, 0.5f * (x * x + y * y + z * z));
    }

    // ---- my 16 adv points (negated coords) ----
    const float* advb = adv + (size_t)b * NPTS * 3;
    const int base = advChunk * ADV_PER_BLOCK;
    float nax[APT], nay[APT], naz[APT], um[APT];
#pragma unroll
    for (int m = 0; m < APT; m++) {
        int j = base + t + m * BLK;
        nax[m] = -advb[3 * j + 0];
        nay[m] = -advb[3 * j + 1];
        naz[m] = -advb[3 * j + 2];
        um[m] = FLT_MAX;
    }
    __syncthreads();

    // ---- main loop: u = 0.5|o|^2 - a.o ; min over u ----
    float4 c0 = opts[0], c1 = opts[1];
#pragma unroll 1
    for (int k = 0; k < OCHUNK; k += 2) {
        float4 n0 = opts[(k + 2) & (OCHUNK - 1)];   // prefetch (wraps harmlessly)
        float4 n1 = opts[(k + 3) & (OCHUNK - 1)];
#pragma unroll
        for (int m = 0; m < APT; m++) {
            float u0 = fmaf(nax[m], c0.x, fmaf(nay[m], c0.y, fmaf(naz[m], c0.z, c0.w)));
            float u1 = fmaf(nax[m], c1.x, fmaf(nay[m], c1.y, fmaf(naz[m], c1.z, c1.w)));
            um[m] = fminf(fminf(um[m], u0), u1);    // v_min3_f32
        }
        c0 = n0; c1 = n1;
    }

    // ---- epilogue: d = ra + 2*u_min -> partial[split][col range] ----
    float* pb = partial + (size_t)split * TOTAL + (size_t)b * NPTS;
#pragma unroll
    for (int m = 0; m < APT; m++) {
        float ra = fmaf(nax[m], nax[m], fmaf(nay[m], nay[m], naz[m] * naz[m]));
        pb[base + t + m * BLK] = fmaf(2.0f, um[m], ra);
    }

    // ---- column ticket: last of the 32 split-blocks reduces the column ----
    __threadfence();
    if (t == 0) ticket_s = atomicAdd(&colCnt[col], 1u);
    __syncthreads();
    if (ticket_s != OSPLIT - 1) return;
    __threadfence();

    const float4* p4 = (const float4*)partial;
    const int colOff4 = (b * NPTS + base) >> 2;      // float4 index of column start
    float wsum = 0.0f;
#pragma unroll
    for (int q = 0; q < ADV_PER_BLOCK / 4 / BLK; q++) {   // 4 iterations
        int j = colOff4 + t + q * BLK;
        float4 mn = p4[j];
#pragma unroll 4
        for (int s = 1; s < OSPLIT; s++) {
            float4 v = p4[(size_t)s * (TOTAL / 4) + j];
            mn.x = fminf(mn.x, v.x); mn.y = fminf(mn.y, v.y);
            mn.z = fminf(mn.z, v.z); mn.w = fminf(mn.w, v.w);
        }
        wsum += (mn.x + mn.y) + (mn.z + mn.w);
    }
    wsum *= w[b];

    red[t] = wsum;
    __syncthreads();
    for (int s = BLK / 2; s > 0; s >>= 1) {
        if (t < s) red[t] += red[t + s];
        __syncthreads();
    }
    if (t == 0) {
        colsum[col] = red[0];
        __threadfence();
        unsigned int t2 = atomicAdd(cnt2, 1u);
        if (t2 == NCOL - 1) {
            __threadfence();
            float s = 0.0f;
            for (int c = 0; c < NCOL; c++) s += colsum[c];
            out[0] = s * (1.0f / (float)TOTAL);
        }
    }
}

extern "C" void kernel_launch(void* const* d_in, const int* in_sizes, int n_in,
                              void* d_out, int out_size, void* d_ws, size_t ws_size,
                              hipStream_t stream) {
    const float* adv = (const float*)d_in[0];   // [8,8192,3] f32
    const float* ori = (const float*)d_in[1];   // [8,8192,3] f32
    const float* w   = (const float*)d_in[2];   // [8] f32
    float* out = (float*)d_out;

    float* partial = (float*)d_ws;                               // 8 MB
    char* tail = (char*)d_ws + PART_BYTES;
    float* colsum = (float*)tail;                                // 16 floats
    unsigned int* colCnt = (unsigned int*)(tail + 64);           // 16 uints
    unsigned int* cnt2 = (unsigned int*)(tail + 128);            // 1 uint

    // Node 1: zero colsum+counters (192 B). Node 2: the fused kernel.
    hipMemsetAsync(tail, 0, 192, stream);
    hipLaunchKernelGGL(chamfer_fused, dim3(GRID_MAIN), dim3(BLK), 0, stream,
                       adv, ori, w, partial, colsum, colCnt, cnt2, out);
}

// Round 4
// 123.031 us; speedup vs baseline: 1.4280x; 1.4280x over previous
//
#include <hip/hip_runtime.h>
#include <float.h>

// Problem constants (B=8, N=8192, D=3)
#define NB 8
#define NPTS 8192
#define TOTAL (NB * NPTS)            // 65536 adv points
#define BLK 256
#define APT 16                       // adv points per thread
#define OSPLIT 64                    // ori-dimension split (blocks per column)
#define OCHUNK (NPTS / OSPLIT)       // 128 ori points per block (2 KB LDS)
#define ADV_PER_BLOCK (BLK * APT)    // 4096
#define ADV_CHUNKS (NPTS / ADV_PER_BLOCK)   // 2
#define GRID_MAIN (NB * OSPLIT * ADV_CHUNKS) // 1024 blocks -> 4 blocks/CU, 16 waves/CU
#define PART_BYTES ((size_t)OSPLIT * TOTAL * sizeof(float))  // 16 MB

// ---------------- main kernel: partial mins only ----------------
// Block = (batch b, advChunk of 4096 adv pts, split of 128 ori pts).
// Ori pts staged in LDS as (x,y,z,0.5*|o|^2); each thread owns 16 adv pts in
// registers. Inner loop per 2 ori pts x 1 adv pt: 6 v_fma_f32 + 1 v_min3_f32
// (3.5 instr/pair -> 24 us issue floor). One-iteration LDS prefetch: 112 VALU
// instr (~224 cyc) covers the ~120 cyc ds_read_b128 latency.
// u = 0.5|o|^2 - a.o ; d = |a|^2 + 2*min(u) recovered at the end.
__global__ __launch_bounds__(BLK) void chamfer_main(const float* __restrict__ adv,
                                                    const float* __restrict__ ori,
                                                    float* __restrict__ partial) {
    const int bx = blockIdx.x;
    const int b = bx >> 7;                 // 128 blocks per batch
    const int rem = bx & 127;
    const int advChunk = rem & (ADV_CHUNKS - 1);
    const int split = rem >> 1;
    const int t = threadIdx.x;

    __shared__ float4 opts[OCHUNK];        // 2 KB
    const float* orib = ori + ((size_t)b * NPTS + (size_t)split * OCHUNK) * 3;
    if (t < OCHUNK) {
        float x = orib[3 * t + 0], y = orib[3 * t + 1], z = orib[3 * t + 2];
        opts[t] = make_float4(x, y, z, 0.5f * (x * x + y * y + z * z));
    }

    const float* advb = adv + (size_t)b * NPTS * 3;
    const int base = advChunk * ADV_PER_BLOCK;
    float nax[APT], nay[APT], naz[APT], um[APT];
#pragma unroll
    for (int m = 0; m < APT; m++) {
        int j = base + t + m * BLK;
        nax[m] = -advb[3 * j + 0];
        nay[m] = -advb[3 * j + 1];
        naz[m] = -advb[3 * j + 2];
        um[m] = FLT_MAX;
    }
    __syncthreads();

    float4 c0 = opts[0], c1 = opts[1];
#pragma unroll 1
    for (int k = 0; k < OCHUNK; k += 2) {
        float4 n0 = opts[(k + 2) & (OCHUNK - 1)];   // branchless wrap prefetch
        float4 n1 = opts[(k + 3) & (OCHUNK - 1)];
#pragma unroll
        for (int m = 0; m < APT; m++) {
            float u0 = fmaf(nax[m], c0.x, fmaf(nay[m], c0.y, fmaf(naz[m], c0.z, c0.w)));
            float u1 = fmaf(nax[m], c1.x, fmaf(nay[m], c1.y, fmaf(naz[m], c1.z, c1.w)));
            um[m] = fminf(fminf(um[m], u0), u1);    // v_min3_f32
        }
        c0 = n0; c1 = n1;
    }

    float* pb = partial + (size_t)split * TOTAL + (size_t)b * NPTS;
#pragma unroll
    for (int m = 0; m < APT; m++) {
        float ra = fmaf(nax[m], nax[m], fmaf(nay[m], nay[m], naz[m] * naz[m]));
        pb[base + t + m * BLK] = fmaf(2.0f, um[m], ra);
    }
}

// ---------------- reduce: min over splits + weighted mean ----------------
__global__ __launch_bounds__(BLK) void reduce_partial(const float* __restrict__ partial,
                                                      const float* __restrict__ w,
                                                      float* __restrict__ out) {
    const int g = blockIdx.x * BLK + threadIdx.x;   // one adv point per thread
    float m = partial[g];
#pragma unroll 8
    for (int s = 1; s < OSPLIT; s++) m = fminf(m, partial[(size_t)s * TOTAL + g]);
    float v = m * w[g >> 13];                       // 8192 points per batch

    __shared__ float red[BLK];
    red[threadIdx.x] = v;
    __syncthreads();
    for (int s = BLK / 2; s > 0; s >>= 1) {
        if (threadIdx.x < s) red[threadIdx.x] += red[threadIdx.x + s];
        __syncthreads();
    }
    if (threadIdx.x == 0) atomicAdd(out, red[0] * (1.0f / (float)TOTAL));
}

extern "C" void kernel_launch(void* const* d_in, const int* in_sizes, int n_in,
                              void* d_out, int out_size, void* d_ws, size_t ws_size,
                              hipStream_t stream) {
    const float* adv = (const float*)d_in[0];   // [8,8192,3] f32
    const float* ori = (const float*)d_in[1];   // [8,8192,3] f32
    const float* w   = (const float*)d_in[2];   // [8] f32
    float* out = (float*)d_out;
    float* partial = (float*)d_ws;              // 16 MB (ws_size >= 16MB verified in R2)

    hipMemsetAsync(out, 0, sizeof(float), stream);
    hipLaunchKernelGGL(chamfer_main, dim3(GRID_MAIN), dim3(BLK), 0, stream,
                       adv, ori, partial);
    hipLaunchKernelGGL(reduce_partial, dim3(TOTAL / BLK), dim3(BLK), 0, stream,
                       partial, w, out);
}

// Round 5
// 113.925 us; speedup vs baseline: 1.5422x; 1.0799x over previous
//
#include <hip/hip_runtime.h>
#include <float.h>

// Problem constants (B=8, N=8192, D=3)
#define NB 8
#define NPTS 8192
#define TOTAL (NB * NPTS)           // 65536
#define BLK 256
#define WAVES_PER_BLOCK 4
#define ADV_PER_WAVE 32             // two 16-column MFMA groups per wave
#define ADV_PER_BLOCK (WAVES_PER_BLOCK * ADV_PER_WAVE)  // 128
#define GRID_MAIN (TOTAL / ADV_PER_BLOCK)               // 512 blocks (2/CU)
#define OCH 2048                    // ori records per LDS chunk (64 KB)
#define NCHUNK (NPTS / OCH)         // 4
#define REC_SHORTS 16               // 32 B per ori record
#define BF16_ONE 0x3F80

typedef short short8 __attribute__((ext_vector_type(8)));
typedef float floatx4 __attribute__((ext_vector_type(4)));

// round-to-nearest-even float -> bf16 bits (no NaN inputs here)
__device__ __forceinline__ unsigned short f2bf(float f) {
    unsigned int u = __float_as_uint(f);
    unsigned int r = (u + 0x7FFFu + ((u >> 16) & 1u)) >> 16;
    return (unsigned short)r;
}
__device__ __forceinline__ float bf2f(unsigned short h) {
    return __uint_as_float(((unsigned int)h) << 16);
}

// ---- prologue: per ori point, store 16 bf16 = the A-side K-vector halves ----
// rec = [ohx,ohy,ohz, ohx,ohy,ohz, olx,oly | olz, roh, rol, 0,0,0,0,0]
__global__ __launch_bounds__(BLK) void build_recs(const float* __restrict__ ori,
                                                  unsigned short* __restrict__ recs) {
    int g = blockIdx.x * BLK + threadIdx.x;       // one ori point per thread
    float x = ori[3 * g + 0], y = ori[3 * g + 1], z = ori[3 * g + 2];
    unsigned short hx = f2bf(x), hy = f2bf(y), hz = f2bf(z);
    unsigned short lx = f2bf(x - bf2f(hx));
    unsigned short ly = f2bf(y - bf2f(hy));
    unsigned short lz = f2bf(z - bf2f(hz));
    float ro = fmaf(x, x, fmaf(y, y, z * z));
    unsigned short rh = f2bf(ro), rl = f2bf(ro - bf2f(rh));
    __align__(16) unsigned short r[16] = {hx, hy, hz, hx, hy, hz, lx, ly,
                                          lz, rh, rl, 0, 0, 0, 0, 0};
    float4* dst = (float4*)(recs + (size_t)g * REC_SHORTS);
    dst[0] = ((float4*)r)[0];
    dst[1] = ((float4*)r)[1];
}

// ---- main: MFMA brute-force nearest-ori per adv point ----
// Wave owns 32 adv cols (2 B-frags). Per 16-ori tile: one ds_read_b128 (A-frag,
// quads 0/1; quads 2/3 read a 16B zero pad) + 2 MFMA + 6 min-fold VALU.
// D[m][n] = ro_m - 2*dot(o_m, a_n) (hi/lo split exact in fp32 accum);
// d_n = ra_n + min_m D[m][n].
__global__ __launch_bounds__(BLK) void chamfer_mfma(const float* __restrict__ adv,
                                                    const unsigned short* __restrict__ recs,
                                                    float* __restrict__ mins) {
    __shared__ __align__(16) unsigned short lrec[OCH * REC_SHORTS + 8]; // 64 KB + 16 B pad
    const int tid = threadIdx.x;
    const int wave = tid >> 6, lane = tid & 63;
    const int quad = lane >> 4, col = lane & 15;
    const int b = blockIdx.x >> 6;                       // 64 blocks per batch
    const int advBase = (blockIdx.x & 63) * ADV_PER_BLOCK + wave * ADV_PER_WAVE;

    if (tid < 8) lrec[OCH * REC_SHORTS + tid] = 0;       // the zero record

    // Build the two B-fragments (adv side): per quad k-slices of
    // [-2ah(3), -2al(3), -2ah(3), 1, 1, 0...]
    const float* advb = adv + (size_t)b * NPTS * 3;
    short8 bfr[2];
    float ra[2], um[2] = {FLT_MAX, FLT_MAX};
#pragma unroll
    for (int g2 = 0; g2 < 2; g2++) {
        int j = advBase + g2 * 16 + col;
        float x = advb[3 * j + 0], y = advb[3 * j + 1], z = advb[3 * j + 2];
        ra[g2] = fmaf(x, x, fmaf(y, y, z * z));
        unsigned short hx = f2bf(x), hy = f2bf(y), hz = f2bf(z);
        float fhx = bf2f(hx), fhy = bf2f(hy), fhz = bf2f(hz);
        unsigned short nhx = f2bf(-2.0f * fhx), nhy = f2bf(-2.0f * fhy), nhz = f2bf(-2.0f * fhz);
        unsigned short nlx = f2bf(-2.0f * bf2f(f2bf(x - fhx)));
        unsigned short nly = f2bf(-2.0f * bf2f(f2bf(y - fhy)));
        unsigned short nlz = f2bf(-2.0f * bf2f(f2bf(z - fhz)));
        __align__(16) unsigned short e[8] = {0, 0, 0, 0, 0, 0, 0, 0};
        if (quad == 0) {
            e[0] = nhx; e[1] = nhy; e[2] = nhz;
            e[3] = nlx; e[4] = nly; e[5] = nlz;
            e[6] = nhx; e[7] = nhy;
        } else if (quad == 1) {
            e[0] = nhz; e[1] = BF16_ONE; e[2] = BF16_ONE;
        }
        bfr[g2] = *(short8*)e;
    }

    // per-lane LDS A-frag cursor (ushort units): quads 0/1 walk records,
    // quads 2/3 pinned to the zero pad.
    int off = (quad < 2) ? (col * 16 + quad * 8) : (OCH * REC_SHORTS);
    const int stride = (quad < 2) ? 256 : 0;             // 16 records * 16 ushorts

    const float4* gsrc = (const float4*)(recs + (size_t)b * NPTS * REC_SHORTS);
    const floatx4 zero4 = {0.0f, 0.0f, 0.0f, 0.0f};

    for (int c = 0; c < NCHUNK; c++) {
        __syncthreads();
        // stage 2048 records = 4096 float4
#pragma unroll
        for (int i = 0; i < (OCH * 2) / BLK; i++)        // 16 per thread
            ((float4*)lrec)[i * BLK + tid] = gsrc[(size_t)c * OCH * 2 + i * BLK + tid];
        __syncthreads();

        int o = off;
#pragma unroll 4
        for (int t = 0; t < OCH / 16; t++) {             // 128 tiles per chunk
            short8 af = *(const short8*)&lrec[o];
            o += stride;
            floatx4 d0 = __builtin_amdgcn_mfma_f32_16x16x32_bf16(af, bfr[0], zero4, 0, 0, 0);
            floatx4 d1 = __builtin_amdgcn_mfma_f32_16x16x32_bf16(af, bfr[1], zero4, 0, 0, 0);
            um[0] = fminf(um[0], fminf(fminf(d0.x, d0.y), fminf(d0.z, d0.w)));
            um[1] = fminf(um[1], fminf(fminf(d1.x, d1.y), fminf(d1.z, d1.w)));
        }
    }

    // fold the 4 quads (rows m = quad*4+reg cover 0..15 across quads)
#pragma unroll
    for (int g2 = 0; g2 < 2; g2++) {
        float v = um[g2];
        v = fminf(v, __shfl_xor(v, 16, 64));
        v = fminf(v, __shfl_xor(v, 32, 64));
        um[g2] = v;
    }
    if (quad == 0) {
        int o = b * NPTS + advBase + col;
        mins[o] = ra[0] + um[0];
        mins[o + 16] = ra[1] + um[1];
    }
}

// ---- weighted mean of the 65536 mins ----
__global__ __launch_bounds__(BLK) void reduce_mins(const float* __restrict__ mins,
                                                   const float* __restrict__ w,
                                                   float* __restrict__ out) {
    int g = blockIdx.x * BLK + threadIdx.x;
    float v = mins[g] * w[g >> 13];                      // 8192 pts per batch
    __shared__ float red[BLK];
    red[threadIdx.x] = v;
    __syncthreads();
    for (int s = BLK / 2; s > 0; s >>= 1) {
        if (threadIdx.x < s) red[threadIdx.x] += red[threadIdx.x + s];
        __syncthreads();
    }
    if (threadIdx.x == 0) atomicAdd(out, red[0] * (1.0f / (float)TOTAL));
}

extern "C" void kernel_launch(void* const* d_in, const int* in_sizes, int n_in,
                              void* d_out, int out_size, void* d_ws, size_t ws_size,
                              hipStream_t stream) {
    const float* adv = (const float*)d_in[0];   // [8,8192,3] f32
    const float* ori = (const float*)d_in[1];   // [8,8192,3] f32
    const float* w   = (const float*)d_in[2];   // [8] f32
    float* out = (float*)d_out;

    unsigned short* recs = (unsigned short*)d_ws;                    // 2 MB
    float* mins = (float*)((char*)d_ws + (size_t)TOTAL * REC_SHORTS * sizeof(unsigned short)); // 256 KB

    hipMemsetAsync(out, 0, sizeof(float), stream);
    hipLaunchKernelGGL(build_recs, dim3(TOTAL / BLK), dim3(BLK), 0, stream, ori, recs);
    hipLaunchKernelGGL(chamfer_mfma, dim3(GRID_MAIN), dim3(BLK), 0, stream, adv, recs, mins);
    hipLaunchKernelGGL(reduce_mins, dim3(TOTAL / BLK), dim3(BLK), 0, stream, mins, w, out);
}

// Round 6
// 92.393 us; speedup vs baseline: 1.9015x; 1.2330x over previous
//
#include <hip/hip_runtime.h>
#include <float.h>

// Problem constants (B=8, N=8192, D=3)
#define NB 8
#define NPTS 8192
#define TOTAL (NB * NPTS)             // 65536
#define BLK 256
#define WAVES 4
#define ADV_PER_WAVE 64               // two 32-col MFMA groups per wave
#define ADV_PER_BLOCK (WAVES * ADV_PER_WAVE)   // 256
#define ADV_BLOCKS (TOTAL / ADV_PER_BLOCK)     // 256 (32 per batch)
#define OSPLIT 4                      // ori split -> partial mins
#define OSLICE (NPTS / OSPLIT)        // 2048 ori records per block
#define OCH 1024                      // records per LDS chunk (32 KB)
#define NCHUNK (OSLICE / OCH)         // 2
#define REC_SHORTS 16                 // 32 B per ori record
#define GRID_MAIN (ADV_BLOCKS * OSPLIT)        // 1024 blocks -> 16 waves/CU
#define BF16_ONE 0x3F80

typedef short short8 __attribute__((ext_vector_type(8)));
typedef float floatx16 __attribute__((ext_vector_type(16)));

__device__ __forceinline__ unsigned short f2bf(float f) {   // RNE, no NaNs here
    unsigned int u = __float_as_uint(f);
    return (unsigned short)((u + 0x7FFFu + ((u >> 16) & 1u)) >> 16);
}
__device__ __forceinline__ float bf2f(unsigned short h) {
    return __uint_as_float(((unsigned int)h) << 16);
}

// K-slot map (k = A-row contraction index, 11 used of 16):
//  k0..2 : oh * (-2 ah)    k3..5 : ol * (-2 ah)    k6..8 : oh * (-2 al)
//  k9    : ro_hi * 1       k10   : ro_lo * 1       k11..15 : 0
// A record (ori): [ohx,ohy,ohz, olx,oly,olz, ohx,ohy | ohz, roh, rol, 0x5]
__global__ __launch_bounds__(BLK) void build_recs(const float* __restrict__ ori,
                                                  unsigned short* __restrict__ recs) {
    int g = blockIdx.x * BLK + threadIdx.x;        // one ori point per thread
    float x = ori[3 * g + 0], y = ori[3 * g + 1], z = ori[3 * g + 2];
    unsigned short hx = f2bf(x), hy = f2bf(y), hz = f2bf(z);
    unsigned short lx = f2bf(x - bf2f(hx));
    unsigned short ly = f2bf(y - bf2f(hy));
    unsigned short lz = f2bf(z - bf2f(hz));
    float ro = fmaf(x, x, fmaf(y, y, z * z));
    unsigned short rh = f2bf(ro), rl = f2bf(ro - bf2f(rh));
    __align__(16) unsigned short r[16] = {hx, hy, hz, lx, ly, lz, hx, hy,
                                          hz, rh, rl, 0, 0, 0, 0, 0};
    float4* dst = (float4*)(recs + (size_t)g * REC_SHORTS);
    dst[0] = ((float4*)r)[0];
    dst[1] = ((float4*)r)[1];
}

__device__ __forceinline__ float fold16(floatx16 d, float um) {
    float m0 = fminf(d[0], d[1]),   m1 = fminf(d[2], d[3]);
    float m2 = fminf(d[4], d[5]),   m3 = fminf(d[6], d[7]);
    float m4 = fminf(d[8], d[9]),   m5 = fminf(d[10], d[11]);
    float m6 = fminf(d[12], d[13]), m7 = fminf(d[14], d[15]);
    float n0 = fminf(m0, m1), n1 = fminf(m2, m3);
    float n2 = fminf(m4, m5), n3 = fminf(m6, m7);
    return fminf(um, fminf(fminf(n0, n1), fminf(n2, n3)));
}

// ---- main: 32x32x16 bf16 MFMA brute force ----
// Block = (advBlk of 256 adv pts, split of 2048 ori). Wave owns 64 adv cols.
// Per 32-ori tile: 1 ds_read_b128 (A-frag, all 64 lanes useful) + 2 MFMA +
// tree-min fold. D[m][n] = ro_m - 2 dot(o_m, a_n); d_n = ra_n + min_m D.
__global__ __launch_bounds__(BLK, 4) void chamfer_mfma(const float* __restrict__ adv,
                                                       const unsigned short* __restrict__ recs,
                                                       float* __restrict__ partial) {
    __shared__ __align__(16) unsigned short lrec[OCH * REC_SHORTS];   // 32 KB
    const int tid = threadIdx.x;
    const int wave = tid >> 6, lane = tid & 63;
    const int n32 = lane & 31, half = lane >> 5;
    const int advBlk = blockIdx.x >> 2;            // 0..255
    const int split = blockIdx.x & 3;
    const int b = advBlk >> 5;                     // 32 adv-blocks per batch
    const int advLocal = (advBlk & 31) * ADV_PER_BLOCK + wave * ADV_PER_WAVE;

    // B-fragments (adv side), k-map per half: half0 = {-2ah(3), -2ah(3), -2al(2)},
    // half1 = {-2alz, 1, 1, 0...}
    short8 bfr[2];
    float ra[2], um[2] = {FLT_MAX, FLT_MAX};
    const float* advb = adv + (size_t)b * NPTS * 3;
#pragma unroll
    for (int g2 = 0; g2 < 2; g2++) {
        int j = advLocal + g2 * 32 + n32;
        float x = advb[3 * j + 0], y = advb[3 * j + 1], z = advb[3 * j + 2];
        ra[g2] = fmaf(x, x, fmaf(y, y, z * z));
        unsigned short hx = f2bf(x), hy = f2bf(y), hz = f2bf(z);
        float fhx = bf2f(hx), fhy = bf2f(hy), fhz = bf2f(hz);
        unsigned short nhx = f2bf(-2.0f * fhx), nhy = f2bf(-2.0f * fhy), nhz = f2bf(-2.0f * fhz);
        unsigned short nlx = f2bf(-2.0f * bf2f(f2bf(x - fhx)));
        unsigned short nly = f2bf(-2.0f * bf2f(f2bf(y - fhy)));
        unsigned short nlz = f2bf(-2.0f * bf2f(f2bf(z - fhz)));
        __align__(16) unsigned short e[8] = {0, 0, 0, 0, 0, 0, 0, 0};
        if (half == 0) {
            e[0] = nhx; e[1] = nhy; e[2] = nhz;
            e[3] = nhx; e[4] = nhy; e[5] = nhz;
            e[6] = nlx; e[7] = nly;
        } else {
            e[0] = nlz; e[1] = BF16_ONE; e[2] = BF16_ONE;
        }
        bfr[g2] = *(short8*)e;
    }

    const floatx16 zero = {0.f, 0.f, 0.f, 0.f, 0.f, 0.f, 0.f, 0.f,
                           0.f, 0.f, 0.f, 0.f, 0.f, 0.f, 0.f, 0.f};
    const int lsh = n32 * REC_SHORTS + half * 8;   // per-lane A-frag short offset in tile
    const float4* gsrc = (const float4*)recs;

    for (int c = 0; c < NCHUNK; c++) {
        __syncthreads();
        const float4* src = gsrc + (size_t)(b * NPTS + split * OSLICE + c * OCH) * 2;
#pragma unroll
        for (int i = 0; i < (OCH * 2) / BLK; i++)   // 8 float4 per thread
            ((float4*)lrec)[i * BLK + tid] = src[i * BLK + tid];
        __syncthreads();

#pragma unroll 4
        for (int t = 0; t < OCH / 32; t++) {        // 32 ori-tiles per chunk
            short8 af = *(const short8*)&lrec[t * 32 * REC_SHORTS + lsh];
            floatx16 d0 = __builtin_amdgcn_mfma_f32_32x32x16_bf16(af, bfr[0], zero, 0, 0, 0);
            floatx16 d1 = __builtin_amdgcn_mfma_f32_32x32x16_bf16(af, bfr[1], zero, 0, 0, 0);
            um[0] = fold16(d0, um[0]);
            um[1] = fold16(d1, um[1]);
        }
    }

    // rows covered per lane: half=0 -> {0-3,8-11,16-19,24-27}, half=1 -> rest
#pragma unroll
    for (int g2 = 0; g2 < 2; g2++) {
        float v = fminf(um[g2], __shfl_xor(um[g2], 32, 64));
        if (half == 0) {
            int col = b * NPTS + advLocal + g2 * 32 + n32;
            partial[(size_t)split * TOTAL + col] = ra[g2] + v;
        }
    }
}

// ---- reduce: min over 4 splits + weighted mean ----
__global__ __launch_bounds__(BLK) void reduce_mins(const float* __restrict__ partial,
                                                   const float* __restrict__ w,
                                                   float* __restrict__ out) {
    int g = blockIdx.x * BLK + threadIdx.x;
    float m = partial[g];
#pragma unroll
    for (int s = 1; s < OSPLIT; s++) m = fminf(m, partial[(size_t)s * TOTAL + g]);
    float v = m * w[g >> 13];                       // 8192 pts per batch
    __shared__ float red[BLK];
    red[threadIdx.x] = v;
    __syncthreads();
    for (int s = BLK / 2; s > 0; s >>= 1) {
        if (threadIdx.x < s) red[threadIdx.x] += red[threadIdx.x + s];
        __syncthreads();
    }
    if (threadIdx.x == 0) atomicAdd(out, red[0] * (1.0f / (float)TOTAL));
}

extern "C" void kernel_launch(void* const* d_in, const int* in_sizes, int n_in,
                              void* d_out, int out_size, void* d_ws, size_t ws_size,
                              hipStream_t stream) {
    const float* adv = (const float*)d_in[0];   // [8,8192,3] f32
    const float* ori = (const float*)d_in[1];   // [8,8192,3] f32
    const float* w   = (const float*)d_in[2];   // [8] f32
    float* out = (float*)d_out;

    unsigned short* recs = (unsigned short*)d_ws;                                  // 2 MB
    float* partial = (float*)((char*)d_ws + (size_t)TOTAL * REC_SHORTS * 2);       // 1 MB

    hipMemsetAsync(out, 0, sizeof(float), stream);
    hipLaunchKernelGGL(build_recs, dim3(TOTAL / BLK), dim3(BLK), 0, stream, ori, recs);
    hipLaunchKernelGGL(chamfer_mfma, dim3(GRID_MAIN), dim3(BLK), 0, stream, adv, recs, partial);
    hipLaunchKernelGGL(reduce_mins, dim3(TOTAL / BLK), dim3(BLK), 0, stream, partial, w, out);
}

// Round 7
// 80.662 us; speedup vs baseline: 2.1781x; 1.1454x over previous
//
#include <hip/hip_runtime.h>
#include <float.h>

// Problem constants (B=8, N=8192, D=3)
#define NB 8
#define NPTS 8192
#define TOTAL (NB * NPTS)             // 65536
#define BLK 256
#define WAVES 4
#define ADV_PER_WAVE 128              // four 32-col MFMA groups per wave
#define GROUPS 4
#define ADV_PER_BLOCK (WAVES * ADV_PER_WAVE)   // 512
#define ADV_BLOCKS (TOTAL / ADV_PER_BLOCK)     // 128 (16 per batch)
#define OSPLIT 8                      // ori split -> partial mins
#define OSLICE (NPTS / OSPLIT)        // 1024 ori records per block (32 KB LDS)
#define REC_SHORTS 16                 // 32 B per ori record
#define GRID_MAIN (ADV_BLOCKS * OSPLIT)        // 1024 blocks -> 16 waves/CU
#define BF16_ONE 0x3F80

typedef short short8 __attribute__((ext_vector_type(8)));
typedef float floatx16 __attribute__((ext_vector_type(16)));

__device__ __forceinline__ unsigned short f2bf(float f) {   // RNE, no NaNs here
    unsigned int u = __float_as_uint(f);
    return (unsigned short)((u + 0x7FFFu + ((u >> 16) & 1u)) >> 16);
}
__device__ __forceinline__ float bf2f(unsigned short h) {
    return __uint_as_float(((unsigned int)h) << 16);
}
__device__ __forceinline__ float min3(float a, float b, float c) {
    return fminf(fminf(a, b), c);                 // -> v_min3_f32
}
// 16 accum values + carry-in um in 8 v_min3
__device__ __forceinline__ float fold16(floatx16 d, float um) {
    float t0 = min3(d[0], d[1], d[2]);
    float t1 = min3(d[3], d[4], d[5]);
    float t2 = min3(d[6], d[7], d[8]);
    float t3 = min3(d[9], d[10], d[11]);
    float t4 = min3(d[12], d[13], d[14]);
    float t5 = min3(t0, t1, d[15]);
    float t6 = min3(t2, t3, t4);
    return min3(t5, t6, um);
}

// ---- main: 32x32x16 bf16 MFMA brute force, records built in-prologue ----
// K-slot map (11 of 16 used):
//  k0..2: oh*(-2ah)  k3..5: ol*(-2ah)  k6..8: oh*(-2al)  k9: roh*1  k10: rol*1
// A record (ori): [ohx,ohy,ohz, olx,oly,olz, ohx,ohy | ohz, roh, rol, 0 x5]
// B half0: [-2ahx,-2ahy,-2ahz, -2ahx,-2ahy,-2ahz, -2alx,-2aly]; half1: [-2alz,1,1,0..]
// D[m][n] = ro_m - 2 dot(o_m, a_n)  (hi/lo split, exact in fp32 accum);
// d_n = ra_n + min_m D[m][n]  (ra exact fp32).
__global__ __launch_bounds__(BLK, 4) void chamfer_mfma(const float* __restrict__ adv,
                                                       const float* __restrict__ ori,
                                                       float* __restrict__ partial) {
    __shared__ __align__(16) unsigned short lrec[OSLICE * REC_SHORTS];   // 32 KB
    const int tid = threadIdx.x;
    const int wave = tid >> 6, lane = tid & 63;
    const int n32 = lane & 31, half = lane >> 5;
    const int advBlk = blockIdx.x >> 3;            // 0..127
    const int split = blockIdx.x & 7;
    const int b = advBlk >> 4;                     // 16 adv-blocks per batch
    const int advLocal = (advBlk & 15) * ADV_PER_BLOCK + wave * ADV_PER_WAVE;

    // ---- prologue: build 4 ori records per thread directly into LDS ----
    {
        const float4* op = (const float4*)(ori + (size_t)(b * NPTS + split * OSLICE) * 3);
        float4 f0 = op[tid * 3 + 0], f1 = op[tid * 3 + 1], f2 = op[tid * 3 + 2];
        float px[4] = {f0.x, f0.w, f1.z, f2.y};
        float py[4] = {f0.y, f1.x, f1.w, f2.z};
        float pz[4] = {f0.z, f1.y, f2.x, f2.w};
#pragma unroll
        for (int r = 0; r < 4; r++) {
            float x = px[r], y = py[r], z = pz[r];
            unsigned short hx = f2bf(x), hy = f2bf(y), hz = f2bf(z);
            unsigned short lx = f2bf(x - bf2f(hx));
            unsigned short ly = f2bf(y - bf2f(hy));
            unsigned short lz = f2bf(z - bf2f(hz));
            float ro = fmaf(x, x, fmaf(y, y, z * z));
            unsigned short rh = f2bf(ro), rl = f2bf(ro - bf2f(rh));
            __align__(16) unsigned short rec[16] = {hx, hy, hz, lx, ly, lz, hx, hy,
                                                    hz, rh, rl, 0, 0, 0, 0, 0};
            float4* dst = (float4*)&lrec[(tid * 4 + r) * REC_SHORTS];
            dst[0] = ((float4*)rec)[0];
            dst[1] = ((float4*)rec)[1];
        }
    }

    // ---- B-fragments: 4 groups of 32 adv columns ----
    short8 bfr[GROUPS];
    float ra[GROUPS], um[GROUPS];
    const float* advb = adv + (size_t)b * NPTS * 3;
#pragma unroll
    for (int g = 0; g < GROUPS; g++) {
        int j = advLocal + g * 32 + n32;
        float x = advb[3 * j + 0], y = advb[3 * j + 1], z = advb[3 * j + 2];
        ra[g] = fmaf(x, x, fmaf(y, y, z * z));
        um[g] = FLT_MAX;
        unsigned short hx = f2bf(x), hy = f2bf(y), hz = f2bf(z);
        float fhx = bf2f(hx), fhy = bf2f(hy), fhz = bf2f(hz);
        unsigned short nhx = f2bf(-2.0f * fhx), nhy = f2bf(-2.0f * fhy), nhz = f2bf(-2.0f * fhz);
        unsigned short nlx = f2bf(-2.0f * bf2f(f2bf(x - fhx)));
        unsigned short nly = f2bf(-2.0f * bf2f(f2bf(y - fhy)));
        unsigned short nlz = f2bf(-2.0f * bf2f(f2bf(z - fhz)));
        __align__(16) unsigned short e[8] = {0, 0, 0, 0, 0, 0, 0, 0};
        if (half == 0) {
            e[0] = nhx; e[1] = nhy; e[2] = nhz;
            e[3] = nhx; e[4] = nhy; e[5] = nhz;
            e[6] = nlx; e[7] = nly;
        } else {
            e[0] = nlz; e[1] = BF16_ONE; e[2] = BF16_ONE;
        }
        bfr[g] = *(short8*)e;
    }
    __syncthreads();

    const floatx16 zero = {0.f, 0.f, 0.f, 0.f, 0.f, 0.f, 0.f, 0.f,
                           0.f, 0.f, 0.f, 0.f, 0.f, 0.f, 0.f, 0.f};
    const int lsh = n32 * REC_SHORTS + half * 8;   // per-lane A-frag offset in a tile

    // ---- main loop: 32 ori-tiles; 1 ds_read_b128 feeds 4 MFMAs ----
#pragma unroll 4
    for (int t = 0; t < OSLICE / 32; t++) {
        short8 af = *(const short8*)&lrec[t * 32 * REC_SHORTS + lsh];
#pragma unroll
        for (int g = 0; g < GROUPS; g++) {
            floatx16 d = __builtin_amdgcn_mfma_f32_32x32x16_bf16(af, bfr[g], zero, 0, 0, 0);
            um[g] = fold16(d, um[g]);
        }
    }

    // rows per lane: half=0 -> {0-3,8-11,16-19,24-27}; shfl 32 folds the rest
#pragma unroll
    for (int g = 0; g < GROUPS; g++) {
        float v = fminf(um[g], __shfl_xor(um[g], 32, 64));
        if (half == 0) {
            int col = b * NPTS + advLocal + g * 32 + n32;
            partial[(size_t)split * TOTAL + col] = ra[g] + v;
        }
    }
}

// ---- reduce: min over 8 splits + weighted mean ----
__global__ __launch_bounds__(BLK) void reduce_mins(const float* __restrict__ partial,
                                                   const float* __restrict__ w,
                                                   float* __restrict__ out) {
    int g = blockIdx.x * BLK + threadIdx.x;
    float m = partial[g];
#pragma unroll
    for (int s = 1; s < OSPLIT; s++) m = fminf(m, partial[(size_t)s * TOTAL + g]);
    float v = m * w[g >> 13];                       // 8192 pts per batch
    __shared__ float red[BLK];
    red[threadIdx.x] = v;
    __syncthreads();
    for (int s = BLK / 2; s > 0; s >>= 1) {
        if (threadIdx.x < s) red[threadIdx.x] += red[threadIdx.x + s];
        __syncthreads();
    }
    if (threadIdx.x == 0) atomicAdd(out, red[0] * (1.0f / (float)TOTAL));
}

extern "C" void kernel_launch(void* const* d_in, const int* in_sizes, int n_in,
                              void* d_out, int out_size, void* d_ws, size_t ws_size,
                              hipStream_t stream) {
    const float* adv = (const float*)d_in[0];   // [8,8192,3] f32
    const float* ori = (const float*)d_in[1];   // [8,8192,3] f32
    const float* w   = (const float*)d_in[2];   // [8] f32
    float* out = (float*)d_out;
    float* partial = (float*)d_ws;              // 8 * 64K floats = 2 MB

    hipMemsetAsync(out, 0, sizeof(float), stream);
    hipLaunchKernelGGL(chamfer_mfma, dim3(GRID_MAIN), dim3(BLK), 0, stream,
                       adv, ori, partial);
    hipLaunchKernelGGL(reduce_mins, dim3(TOTAL / BLK), dim3(BLK), 0, stream,
                       partial, w, out);
}

// Round 8
// 80.571 us; speedup vs baseline: 2.1805x; 1.0011x over previous
//
#include <hip/hip_runtime.h>
#include <float.h>

// Problem constants (B=8, N=8192, D=3)
#define NB 8
#define NPTS 8192
#define TOTAL (NB * NPTS)             // 65536
#define BLK 256
#define WAVES 4
#define GROUPS 8                      // 32-col MFMA groups per wave
#define ADV_PER_WAVE (GROUPS * 32)    // 256
#define ADV_PER_BLOCK (WAVES * ADV_PER_WAVE)   // 1024
#define ADV_BLOCKS (TOTAL / ADV_PER_BLOCK)     // 64 (8 per batch)
#define OSPLIT 16                     // ori split -> partial mins
#define OSLICE (NPTS / OSPLIT)        // 512 ori records per block (16 KB LDS)
#define REC_SHORTS 16                 // 32 B per ori record
#define GRID_MAIN (ADV_BLOCKS * OSPLIT)        // 1024 blocks -> 16 waves/CU
#define BF16_ONE 0x3F80

typedef short short8 __attribute__((ext_vector_type(8)));
typedef float floatx16 __attribute__((ext_vector_type(16)));

__device__ __forceinline__ unsigned short f2bf(float f) {   // RNE, no NaNs here
    unsigned int u = __float_as_uint(f);
    return (unsigned short)((u + 0x7FFFu + ((u >> 16) & 1u)) >> 16);
}
__device__ __forceinline__ float bf2f(unsigned short h) {
    return __uint_as_float(((unsigned int)h) << 16);
}
__device__ __forceinline__ float min3(float a, float b, float c) {
    return fminf(fminf(a, b), c);                 // -> v_min3_f32
}
// 16 accum values + carry-in um in 8 v_min3
__device__ __forceinline__ float fold16(floatx16 d, float um) {
    float t0 = min3(d[0], d[1], d[2]);
    float t1 = min3(d[3], d[4], d[5]);
    float t2 = min3(d[6], d[7], d[8]);
    float t3 = min3(d[9], d[10], d[11]);
    float t4 = min3(d[12], d[13], d[14]);
    float t5 = min3(t0, t1, d[15]);
    float t6 = min3(t2, t3, t4);
    return min3(t5, t6, um);
}

// ---- main: 32x32x16 bf16 MFMA brute force, records built in-prologue ----
// K-slot map (11 of 16 used):
//  k0..2: oh*(-2ah)  k3..5: ol*(-2ah)  k6..8: oh*(-2al)  k9: roh*1  k10: rol*1
// A record (ori): [ohx,ohy,ohz, olx,oly,olz, ohx,ohy | ohz, roh, rol, 0 x5]
// B half0: [-2ahx,-2ahy,-2ahz, -2ahx,-2ahy,-2ahz, -2alx,-2aly]; half1: [-2alz,1,1,0..]
// D[m][n] = ro_m - 2 dot(o_m, a_n)  (hi/lo split, exact in fp32 accum);
// d_n = ra_n + min_m D[m][n]  (ra exact fp32).
// Per 32-ori tile: 1 ds_read_b128 feeds 8 independent MFMAs (deep matrix-pipe
// window); folds (8 v_min3 each) retire on the VALU pipe underneath.
__global__ __launch_bounds__(BLK, 4) void chamfer_mfma(const float* __restrict__ adv,
                                                       const float* __restrict__ ori,
                                                       float* __restrict__ partial) {
    __shared__ __align__(16) unsigned short lrec[OSLICE * REC_SHORTS];   // 16 KB
    const int tid = threadIdx.x;
    const int wave = tid >> 6, lane = tid & 63;
    const int n32 = lane & 31, half = lane >> 5;
    const int advBlk = blockIdx.x >> 4;            // 0..63
    const int split = blockIdx.x & 15;
    const int b = advBlk >> 3;                     // 8 adv-blocks per batch
    const int advLocal = (advBlk & 7) * ADV_PER_BLOCK + wave * ADV_PER_WAVE;

    // ---- prologue: build 2 ori records per thread directly into LDS ----
    {
        const float* orib = ori + (size_t)(b * NPTS + split * OSLICE) * 3;
#pragma unroll
        for (int r = 0; r < 2; r++) {
            int p = tid * 2 + r;
            float x = orib[3 * p + 0], y = orib[3 * p + 1], z = orib[3 * p + 2];
            unsigned short hx = f2bf(x), hy = f2bf(y), hz = f2bf(z);
            unsigned short lx = f2bf(x - bf2f(hx));
            unsigned short ly = f2bf(y - bf2f(hy));
            unsigned short lz = f2bf(z - bf2f(hz));
            float ro = fmaf(x, x, fmaf(y, y, z * z));
            unsigned short rh = f2bf(ro), rl = f2bf(ro - bf2f(rh));
            __align__(16) unsigned short rec[16] = {hx, hy, hz, lx, ly, lz, hx, hy,
                                                    hz, rh, rl, 0, 0, 0, 0, 0};
            float4* dst = (float4*)&lrec[p * REC_SHORTS];
            dst[0] = ((float4*)rec)[0];
            dst[1] = ((float4*)rec)[1];
        }
    }

    // ---- B-fragments: 8 groups of 32 adv columns ----
    short8 bfr[GROUPS];
    float ra[GROUPS], um[GROUPS];
    const float* advb = adv + (size_t)b * NPTS * 3;
#pragma unroll
    for (int g = 0; g < GROUPS; g++) {
        int j = advLocal + g * 32 + n32;
        float x = advb[3 * j + 0], y = advb[3 * j + 1], z = advb[3 * j + 2];
        ra[g] = fmaf(x, x, fmaf(y, y, z * z));
        um[g] = FLT_MAX;
        unsigned short hx = f2bf(x), hy = f2bf(y), hz = f2bf(z);
        float fhx = bf2f(hx), fhy = bf2f(hy), fhz = bf2f(hz);
        unsigned short nhx = f2bf(-2.0f * fhx), nhy = f2bf(-2.0f * fhy), nhz = f2bf(-2.0f * fhz);
        unsigned short nlx = f2bf(-2.0f * bf2f(f2bf(x - fhx)));
        unsigned short nly = f2bf(-2.0f * bf2f(f2bf(y - fhy)));
        unsigned short nlz = f2bf(-2.0f * bf2f(f2bf(z - fhz)));
        __align__(16) unsigned short e[8] = {0, 0, 0, 0, 0, 0, 0, 0};
        if (half == 0) {
            e[0] = nhx; e[1] = nhy; e[2] = nhz;
            e[3] = nhx; e[4] = nhy; e[5] = nhz;
            e[6] = nlx; e[7] = nly;
        } else {
            e[0] = nlz; e[1] = BF16_ONE; e[2] = BF16_ONE;
        }
        bfr[g] = *(short8*)e;
    }
    __syncthreads();

    const floatx16 zero = {0.f, 0.f, 0.f, 0.f, 0.f, 0.f, 0.f, 0.f,
                           0.f, 0.f, 0.f, 0.f, 0.f, 0.f, 0.f, 0.f};
    const int lsh = n32 * REC_SHORTS + half * 8;   // per-lane A-frag offset in a tile

    // ---- main loop: 16 ori-tiles; 1 ds_read_b128 feeds 8 MFMAs ----
#pragma unroll 2
    for (int t = 0; t < OSLICE / 32; t++) {
        short8 af = *(const short8*)&lrec[t * 32 * REC_SHORTS + lsh];
#pragma unroll
        for (int g = 0; g < GROUPS; g++) {
            floatx16 d = __builtin_amdgcn_mfma_f32_32x32x16_bf16(af, bfr[g], zero, 0, 0, 0);
            um[g] = fold16(d, um[g]);
        }
    }

    // rows per lane: half=0 -> {0-3,8-11,16-19,24-27}; shfl 32 folds the rest
#pragma unroll
    for (int g = 0; g < GROUPS; g++) {
        float v = fminf(um[g], __shfl_xor(um[g], 32, 64));
        if (half == 0) {
            int col = b * NPTS + advLocal + g * 32 + n32;
            partial[(size_t)split * TOTAL + col] = ra[g] + v;
        }
    }
}

// ---- reduce: min over 16 splits + weighted mean (float4 per thread) ----
__global__ __launch_bounds__(BLK) void reduce_mins(const float* __restrict__ partial,
                                                   const float* __restrict__ w,
                                                   float* __restrict__ out) {
    const float4* p4 = (const float4*)partial;
    int g4 = blockIdx.x * BLK + threadIdx.x;        // 16384 float4 groups
    float4 m = p4[g4];
#pragma unroll
    for (int s = 1; s < OSPLIT; s++) {
        float4 v = p4[(size_t)s * (TOTAL / 4) + g4];
        m.x = fminf(m.x, v.x); m.y = fminf(m.y, v.y);
        m.z = fminf(m.z, v.z); m.w = fminf(m.w, v.w);
    }
    // 4 consecutive points share a batch (batch stride 8192 = 2048 float4)
    float v = ((m.x + m.y) + (m.z + m.w)) * w[g4 >> 11];

    __shared__ float red[BLK];
    red[threadIdx.x] = v;
    __syncthreads();
    for (int s = BLK / 2; s > 0; s >>= 1) {
        if (threadIdx.x < s) red[threadIdx.x] += red[threadIdx.x + s];
        __syncthreads();
    }
    if (threadIdx.x == 0) atomicAdd(out, red[0] * (1.0f / (float)TOTAL));
}

extern "C" void kernel_launch(void* const* d_in, const int* in_sizes, int n_in,
                              void* d_out, int out_size, void* d_ws, size_t ws_size,
                              hipStream_t stream) {
    const float* adv = (const float*)d_in[0];   // [8,8192,3] f32
    const float* ori = (const float*)d_in[1];   // [8,8192,3] f32
    const float* w   = (const float*)d_in[2];   // [8] f32
    float* out = (float*)d_out;
    float* partial = (float*)d_ws;              // 16 * 64K floats = 4 MB

    hipMemsetAsync(out, 0, sizeof(float), stream);
    hipLaunchKernelGGL(chamfer_mfma, dim3(GRID_MAIN), dim3(BLK), 0, stream,
                       adv, ori, partial);
    hipLaunchKernelGGL(reduce_mins, dim3(TOTAL / 4 / BLK), dim3(BLK), 0, stream,
                       partial, w, out);
}

// Round 9
// 78.929 us; speedup vs baseline: 2.2259x; 1.0208x over previous
//
#include <hip/hip_runtime.h>
#include <float.h>

// Problem constants (B=8, N=8192, D=3)
#define NB 8
#define NPTS 8192
#define TOTAL (NB * NPTS)             // 65536
#define BLK 256
#define WAVES 4
#define GROUPS 8                      // 32-col MFMA groups per wave
#define ADV_PER_WAVE (GROUPS * 32)    // 256
#define ADV_PER_BLOCK (WAVES * ADV_PER_WAVE)   // 1024
#define ADV_BLOCKS (TOTAL / ADV_PER_BLOCK)     // 64 (8 per batch)
#define OSPLIT 16                     // ori split -> partial mins
#define OSLICE (NPTS / OSPLIT)        // 512 ori records per block (16 KB LDS)
#define REC_SHORTS 16                 // 32 B per ori record
#define GRID_MAIN (ADV_BLOCKS * OSPLIT)        // 1024 blocks -> 16 waves/CU
#define BF16_ONE 0x3F80

typedef short short8 __attribute__((ext_vector_type(8)));
typedef float floatx16 __attribute__((ext_vector_type(16)));

__device__ __forceinline__ unsigned short f2bf(float f) {   // RNE, no NaNs here
    unsigned int u = __float_as_uint(f);
    return (unsigned short)((u + 0x7FFFu + ((u >> 16) & 1u)) >> 16);
}
__device__ __forceinline__ float bf2f(unsigned short h) {
    return __uint_as_float(((unsigned int)h) << 16);
}
__device__ __forceinline__ float min3(float a, float b, float c) {
    return fminf(fminf(a, b), c);                 // -> v_min3_f32
}
// 16 accum values + carry-in um in 8 v_min3
__device__ __forceinline__ float fold16(floatx16 d, float um) {
    float t0 = min3(d[0], d[1], d[2]);
    float t1 = min3(d[3], d[4], d[5]);
    float t2 = min3(d[6], d[7], d[8]);
    float t3 = min3(d[9], d[10], d[11]);
    float t4 = min3(d[12], d[13], d[14]);
    float t5 = min3(t0, t1, d[15]);
    float t6 = min3(t2, t3, t4);
    return min3(t5, t6, um);
}

// ---- main: 32x32x16 bf16 MFMA brute force ----
// K-slot map (11 of 16 used):
//  k0..2: oh*(-2ah)  k3..5: ol*(-2ah)  k6..8: oh*(-2al)  k9: roh*1  k10: rol*1
// A record (ori): [ohx,ohy,ohz, olx,oly,olz, ohx,ohy | ohz, roh, rol, 0 x5]
// B half0: [-2ahx,-2ahy,-2ahz, -2ahx,-2ahy,-2ahz, -2alx,-2aly]; half1: [-2alz,1,1,0..]
// D[m][n] = ro_m - 2 dot(o_m, a_n)  (hi/lo split, exact in fp32 accum);
// d_n = ra_n + min_m D[m][n]  (ra exact fp32).
// Prologue is split: threads 0-127 build ori records (float4 loads), threads
// 128-255 stage the 1024-adv block into LDS (coalesced float4); B-frags then
// come from LDS (half-broadcast reads). Block 0 also zeroes out[0] so the
// reduce kernel needs no preceding memset node.
__global__ __launch_bounds__(BLK, 4) void chamfer_mfma(const float* __restrict__ adv,
                                                       const float* __restrict__ ori,
                                                       float* __restrict__ partial,
                                                       float* __restrict__ out) {
    __shared__ __align__(16) unsigned short lrec[OSLICE * REC_SHORTS];   // 16 KB
    __shared__ __align__(16) float advS[ADV_PER_BLOCK * 3];              // 12 KB
    const int tid = threadIdx.x;
    const int wave = tid >> 6, lane = tid & 63;
    const int n32 = lane & 31, half = lane >> 5;
    const int advBlk = blockIdx.x >> 4;            // 0..63
    const int split = blockIdx.x & 15;
    const int b = advBlk >> 3;                     // 8 adv-blocks per batch
    const int advLocal = (advBlk & 7) * ADV_PER_BLOCK;

    if (blockIdx.x == 0 && tid == 0) out[0] = 0.0f;   // replaces memset node

    if (tid < 128) {
        // ---- build 4 ori records from 3 float4 loads ----
        const float4* op = (const float4*)(ori + (size_t)(b * NPTS + split * OSLICE) * 3);
        float4 f0 = op[tid * 3 + 0], f1 = op[tid * 3 + 1], f2 = op[tid * 3 + 2];
        float px[4] = {f0.x, f0.w, f1.z, f2.y};
        float py[4] = {f0.y, f1.x, f1.w, f2.z};
        float pz[4] = {f0.z, f1.y, f2.x, f2.w};
#pragma unroll
        for (int r = 0; r < 4; r++) {
            float x = px[r], y = py[r], z = pz[r];
            unsigned short hx = f2bf(x), hy = f2bf(y), hz = f2bf(z);
            unsigned short lx = f2bf(x - bf2f(hx));
            unsigned short ly = f2bf(y - bf2f(hy));
            unsigned short lz = f2bf(z - bf2f(hz));
            float ro = fmaf(x, x, fmaf(y, y, z * z));
            unsigned short rh = f2bf(ro), rl = f2bf(ro - bf2f(rh));
            __align__(16) unsigned short rec[16] = {hx, hy, hz, lx, ly, lz, hx, hy,
                                                    hz, rh, rl, 0, 0, 0, 0, 0};
            float4* dst = (float4*)&lrec[(tid * 4 + r) * REC_SHORTS];
            dst[0] = ((float4*)rec)[0];
            dst[1] = ((float4*)rec)[1];
        }
    } else {
        // ---- stage 1024 adv points (768 float4) into LDS, coalesced ----
        const int tt = tid - 128;
        const float4* gadv4 = (const float4*)(adv + (size_t)b * NPTS * 3 + (size_t)advLocal * 3);
        float4* s4 = (float4*)advS;
#pragma unroll
        for (int i = 0; i < 6; i++) s4[tt + i * 128] = gadv4[tt + i * 128];
    }
    __syncthreads();

    // ---- B-fragments from LDS (lanes l and l+32 read same addr: broadcast) ----
    short8 bfr[GROUPS];
    float ra[GROUPS], um[GROUPS];
#pragma unroll
    for (int g = 0; g < GROUPS; g++) {
        int j = (wave * ADV_PER_WAVE + g * 32 + n32) * 3;
        float x = advS[j + 0], y = advS[j + 1], z = advS[j + 2];
        ra[g] = fmaf(x, x, fmaf(y, y, z * z));
        um[g] = FLT_MAX;
        unsigned short hx = f2bf(x), hy = f2bf(y), hz = f2bf(z);
        float fhx = bf2f(hx), fhy = bf2f(hy), fhz = bf2f(hz);
        unsigned short nhx = f2bf(-2.0f * fhx), nhy = f2bf(-2.0f * fhy), nhz = f2bf(-2.0f * fhz);
        unsigned short nlx = f2bf(-2.0f * bf2f(f2bf(x - fhx)));
        unsigned short nly = f2bf(-2.0f * bf2f(f2bf(y - fhy)));
        unsigned short nlz = f2bf(-2.0f * bf2f(f2bf(z - fhz)));
        __align__(16) unsigned short e[8] = {0, 0, 0, 0, 0, 0, 0, 0};
        if (half == 0) {
            e[0] = nhx; e[1] = nhy; e[2] = nhz;
            e[3] = nhx; e[4] = nhy; e[5] = nhz;
            e[6] = nlx; e[7] = nly;
        } else {
            e[0] = nlz; e[1] = BF16_ONE; e[2] = BF16_ONE;
        }
        bfr[g] = *(short8*)e;
    }

    const floatx16 zero = {0.f, 0.f, 0.f, 0.f, 0.f, 0.f, 0.f, 0.f,
                           0.f, 0.f, 0.f, 0.f, 0.f, 0.f, 0.f, 0.f};
    const int lsh = n32 * REC_SHORTS + half * 8;   // per-lane A-frag offset in a tile

    // ---- main loop: 16 ori-tiles; 1 ds_read_b128 feeds 8 MFMAs ----
#pragma unroll 2
    for (int t = 0; t < OSLICE / 32; t++) {
        short8 af = *(const short8*)&lrec[t * 32 * REC_SHORTS + lsh];
#pragma unroll
        for (int g = 0; g < GROUPS; g++) {
            floatx16 d = __builtin_amdgcn_mfma_f32_32x32x16_bf16(af, bfr[g], zero, 0, 0, 0);
            um[g] = fold16(d, um[g]);
        }
    }

    // rows per lane: half=0 -> {0-3,8-11,16-19,24-27}; shfl 32 folds the rest
#pragma unroll
    for (int g = 0; g < GROUPS; g++) {
        float v = fminf(um[g], __shfl_xor(um[g], 32, 64));
        if (half == 0) {
            int col = b * NPTS + advLocal + wave * ADV_PER_WAVE + g * 32 + n32;
            partial[(size_t)split * TOTAL + col] = ra[g] + v;
        }
    }
}

// ---- reduce: min over 16 splits + weighted mean; 256 blocks x 64 threads ----
__global__ __launch_bounds__(64) void reduce_mins(const float* __restrict__ partial,
                                                  const float* __restrict__ w,
                                                  float* __restrict__ out) {
    const float4* p4 = (const float4*)partial;
    int g4 = blockIdx.x * 64 + threadIdx.x;        // 16384 float4 groups
    float4 m = p4[g4];
#pragma unroll
    for (int s = 1; s < OSPLIT; s++) {
        float4 v = p4[(size_t)s * (TOTAL / 4) + g4];
        m.x = fminf(m.x, v.x); m.y = fminf(m.y, v.y);
        m.z = fminf(m.z, v.z); m.w = fminf(m.w, v.w);
    }
    // 4 consecutive points share a batch (batch stride 8192 pts = 2048 float4)
    float v = ((m.x + m.y) + (m.z + m.w)) * w[g4 >> 11];
#pragma unroll
    for (int s = 32; s > 0; s >>= 1) v += __shfl_down(v, s, 64);
    if (threadIdx.x == 0) atomicAdd(out, v * (1.0f / (float)TOTAL));
}

extern "C" void kernel_launch(void* const* d_in, const int* in_sizes, int n_in,
                              void* d_out, int out_size, void* d_ws, size_t ws_size,
                              hipStream_t stream) {
    const float* adv = (const float*)d_in[0];   // [8,8192,3] f32
    const float* ori = (const float*)d_in[1];   // [8,8192,3] f32
    const float* w   = (const float*)d_in[2];   // [8] f32
    float* out = (float*)d_out;
    float* partial = (float*)d_ws;              // 16 * 64K floats = 4 MB

    hipLaunchKernelGGL(chamfer_mfma, dim3(GRID_MAIN), dim3(BLK), 0, stream,
                       adv, ori, partial, out);
    hipLaunchKernelGGL(reduce_mins, dim3(TOTAL / 4 / 64), dim3(64), 0, stream,
                       partial, w, out);
}